// Round 15
// baseline (34.099 us; speedup 1.0000x reference)
//
#include <hip/hip_runtime.h>

#define NPTS 16384
#define NBATCH 256
constexpr int THREADS = 1024;            // 16 waves; one block per row/CU
constexpr int NW      = THREADS / 64;    // 16 waves
// wave w owns points [w*1024,(w+1)*1024); lane i owns 4-pt mini-windows at
// w*1024 + g*256 + i*4 (g=0..3). ALL 32 float4 loads are issued up-front
// into named registers (launch_bounds(1024,2) -> 256-VGPR budget) so each
// wave keeps 32KB in flight; trig consumes window-by-window as vmcnt drains.

__device__ __forceinline__ float4 ld4(const float* p) {
  return *reinterpret_cast<const float4*>(p);
}

__global__ __launch_bounds__(THREADS, 2) void row_loss_kernel(
    const float* __restrict__ o3, const float* __restrict__ s3,
    const float* __restrict__ o2, const float* __restrict__ s2,
    const float* __restrict__ df, float* __restrict__ out) {
  const int b = blockIdx.x;
  const int t = threadIdx.x;
  const int lane = t & 63;
  const int wave = t >> 6;

  __shared__ float wtot[3][NW];
  __shared__ float redbuf[NW];

  const float* r3p = s3 + (size_t)b * 3 * NPTS;
  const float* t3p = r3p + NPTS;
  const float* p3p = r3p + 2 * NPTS;
  const float* r2p = s2 + (size_t)b * 3 * NPTS;
  const float* t2p = r2p + NPTS;
  const float* p2p = r2p + 2 * NPTS;
  const float* dtp = df + (size_t)b * 2 * NPTS;
  const float* dpp = dtp + NPTS;

  const int i0 = wave * 1024 + lane * 4;          // g=0 window
  const int i1 = i0 + 256, i2 = i0 + 512, i3 = i0 + 768;

  // ---- issue ALL loads first: 32 x dwordx4 in flight per lane ----
  float4 R3a = ld4(r3p + i0), T3a = ld4(t3p + i0), P3a = ld4(p3p + i0);
  float4 R2a = ld4(r2p + i0), T2a = ld4(t2p + i0), P2a = ld4(p2p + i0);
  float4 DTa = ld4(dtp + i0), DPa = ld4(dpp + i0);
  float4 R3b = ld4(r3p + i1), T3b = ld4(t3p + i1), P3b = ld4(p3p + i1);
  float4 R2b = ld4(r2p + i1), T2b = ld4(t2p + i1), P2b = ld4(p2p + i1);
  float4 DTb = ld4(dtp + i1), DPb = ld4(dpp + i1);
  float4 R3c = ld4(r3p + i2), T3c = ld4(t3p + i2), P3c = ld4(p3p + i2);
  float4 R2c = ld4(r2p + i2), T2c = ld4(t2p + i2), P2c = ld4(p2p + i2);
  float4 DTc = ld4(dtp + i2), DPc = ld4(dpp + i2);
  float4 R3d = ld4(r3p + i3), T3d = ld4(t3p + i3), P3d = ld4(p3p + i3);
  float4 R2d = ld4(r2p + i3), T2d = ld4(t2p + i3), P2d = ld4(p2p + i3);
  float4 DTd = ld4(dtp + i3), DPd = ld4(dpp + i3);

  float px[4][4], py[4][4], pz[4][4];   // inclusive prefix within mini-window
  float mx[4], my[4], mz[4];            // mini-window totals

  #define DO_WINDOW(g, R3, T3, P3, R2, T2, P2, DT, DP)                        \
    {                                                                         \
      float sx = 0.f, sy = 0.f, sz = 0.f;                                     \
      _Pragma("unroll")                                                       \
      for (int k = 0; k < 4; ++k) {                                           \
        float r3v = ((const float*)&R3)[k];                                   \
        float th3 = ((const float*)&T3)[k] + ((const float*)&DT)[k];          \
        float ph3 = ((const float*)&P3)[k] + ((const float*)&DP)[k];          \
        float r2v = ((const float*)&R2)[k];                                   \
        float th2 = ((const float*)&T2)[k];                                   \
        float ph2 = ((const float*)&P2)[k];                                   \
        float st3 = __sinf(th3), ct3 = __cosf(th3);                           \
        float sp3 = __sinf(ph3), cp3 = __cosf(ph3);                           \
        float st2 = __sinf(th2), ct2 = __cosf(th2);                           \
        float sp2 = __sinf(ph2), cp2 = __cosf(ph2);                           \
        sx += r3v * st3 * cp3 - r2v * st2 * cp2; px[g][k] = sx;               \
        sy += r3v * st3 * sp3 - r2v * st2 * sp2; py[g][k] = sy;               \
        sz += r3v * ct3 - r2v * ct2;             pz[g][k] = sz;               \
      }                                                                       \
      mx[g] = sx; my[g] = sy; mz[g] = sz;                                     \
    }

  DO_WINDOW(0, R3a, T3a, P3a, R2a, T2a, P2a, DTa, DPa)
  DO_WINDOW(1, R3b, T3b, P3b, R2b, T2b, P2b, DTb, DPb)
  DO_WINDOW(2, R3c, T3c, P3c, R2c, T2c, P2c, DTc, DPc)
  DO_WINDOW(3, R3d, T3d, P3d, R2d, T2d, P2d, DTd, DPd)
  #undef DO_WINDOW

  // ---- wave scan in j-order (g-major, then lane) ----
  float runx = 0.f, runy = 0.f, runz = 0.f;
  float segx[4], segy[4], segz[4];
  #pragma unroll
  for (int g = 0; g < 4; ++g) {
    float ix = mx[g], iy = my[g], iz = mz[g];
    #pragma unroll
    for (int off = 1; off < 64; off <<= 1) {
      float ax = __shfl_up(ix, off, 64);
      float ay = __shfl_up(iy, off, 64);
      float az = __shfl_up(iz, off, 64);
      if (lane >= off) { ix += ax; iy += ay; iz += az; }
    }
    segx[g] = runx + ix - mx[g];
    segy[g] = runy + iy - my[g];
    segz[g] = runz + iz - mz[g];
    runx += __shfl(ix, 63, 64);
    runy += __shfl(iy, 63, 64);
    runz += __shfl(iz, 63, 64);
  }

  // ---- block scan over wave totals ----
  if (lane == 0) { wtot[0][wave] = runx; wtot[1][wave] = runy; wtot[2][wave] = runz; }
  __syncthreads();

  float wx = 0.f, wy = 0.f, wz = 0.f;
  #pragma unroll
  for (int w = 0; w < NW; ++w) {
    if (w < wave) { wx += wtot[0][w]; wy += wtot[1][w]; wz += wtot[2][w]; }
  }

  const float ox = o3[b * 3 + 0] - o2[b * 3 + 0];
  const float oy = o3[b * 3 + 1] - o2[b * 3 + 1];
  const float oz = o3[b * 3 + 2] - o2[b * 3 + 2];
  const float bx = ox + wx, by = oy + wy, bz = oz + wz;

  // ---- abs over in-register prefixes ----
  float acc = 0.f;
  #pragma unroll
  for (int g = 0; g < 4; ++g) {
    const float gx = bx + segx[g], gy = by + segy[g], gz = bz + segz[g];
    #pragma unroll
    for (int k = 0; k < 4; ++k) {
      acc += fabsf(gx + px[g][k]) + fabsf(gy + py[g][k]) + fabsf(gz + pz[g][k]);
    }
  }
  if (t == 0) acc += fabsf(ox) + fabsf(oy) + fabsf(oz);  // j=0 cumsum term

  // ---- block reduction + one atomic per row ----
  #pragma unroll
  for (int off = 32; off > 0; off >>= 1) acc += __shfl_down(acc, off, 64);
  if (lane == 0) redbuf[wave] = acc;
  __syncthreads();
  if (t == 0) {
    float s = 0.f;
    #pragma unroll
    for (int w = 0; w < NW; ++w) s += redbuf[w];
    atomicAdd(out, s * (1.0f / (float)(NPTS + 1)));
  }
}

extern "C" void kernel_launch(void* const* d_in, const int* in_sizes, int n_in,
                              void* d_out, int out_size, void* d_ws, size_t ws_size,
                              hipStream_t stream) {
  const float* o3 = (const float*)d_in[0];  // origin_3D      (B,3,1)
  const float* s3 = (const float*)d_in[1];  // spherical_3D   (B,3,N)
  const float* o2 = (const float*)d_in[2];  // origin_2D      (B,3,1)
  const float* s2 = (const float*)d_in[3];  // spherical_2D   (B,3,N)
  const float* df = (const float*)d_in[4];  // deformation    (B,2,N)
  float* out = (float*)d_out;

  // out accumulates via atomicAdd; harness doesn't re-zero between replays.
  hipMemsetAsync(out, 0, sizeof(float) * out_size, stream);
  row_loss_kernel<<<NBATCH, THREADS, 0, stream>>>(o3, s3, o2, s2, df, out);
}

// Round 17
// 32.217 us; speedup vs baseline: 1.0584x; 1.0584x over previous
//
#include <hip/hip_runtime.h>

#define NPTS 16384
#define NBATCH 256
constexpr int THREADS = 1024;            // 16 waves; one block per row/CU
constexpr int NW      = THREADS / 64;    // 16 waves
// R14 base (33.5us) with NON-TEMPORAL loads: read-once streams bypass L2/L3
// allocation (nt flag). Everything else unchanged.

typedef float f32x4 __attribute__((ext_vector_type(4)));

__device__ __forceinline__ f32x4 ld4nt(const float* p) {
  return __builtin_nontemporal_load(reinterpret_cast<const f32x4*>(p));
}

__global__ __launch_bounds__(THREADS, 4) void row_loss_kernel(
    const float* __restrict__ o3, const float* __restrict__ s3,
    const float* __restrict__ o2, const float* __restrict__ s2,
    const float* __restrict__ df, float* __restrict__ out) {
  const int b = blockIdx.x;
  const int t = threadIdx.x;
  const int lane = t & 63;
  const int wave = t >> 6;

  __shared__ float wtot[3][NW][4];   // per-(wave, j-window) totals
  __shared__ float redbuf[NW];

  const float* r3p = s3 + (size_t)b * 3 * NPTS;
  const float* t3p = r3p + NPTS;
  const float* p3p = r3p + 2 * NPTS;
  const float* r2p = s2 + (size_t)b * 3 * NPTS;
  const float* t2p = r2p + NPTS;
  const float* p2p = r2p + 2 * NPTS;
  const float* dtp = df + (size_t)b * 2 * NPTS;
  const float* dpp = dtp + NPTS;

  const int wbase = wave * 1024;
  const int rot = (wave + b) & 3;

  // ---- Phase 1: rotated-window nt-loads, trig, per-window lane-prefix ----
  float px[4][4], py[4][4], pz[4][4];
  #pragma unroll
  for (int g = 0; g < 4; ++g) {
    const int gg = (g + rot) & 3;                 // j-window this g handles
    const int idx = wbase + gg * 256 + lane * 4;
    f32x4 R3 = ld4nt(r3p + idx), T3 = ld4nt(t3p + idx);
    f32x4 P3 = ld4nt(p3p + idx), R2 = ld4nt(r2p + idx);
    f32x4 T2 = ld4nt(t2p + idx), P2 = ld4nt(p2p + idx);
    f32x4 DT = ld4nt(dtp + idx), DP = ld4nt(dpp + idx);
    float sx = 0.f, sy = 0.f, sz = 0.f;
    #pragma unroll
    for (int k = 0; k < 4; ++k) {
      float r3v = R3[k];
      float th3 = T3[k] + DT[k];
      float ph3 = P3[k] + DP[k];
      float r2v = R2[k];
      float th2 = T2[k];
      float ph2 = P2[k];
      float st3 = __sinf(th3), ct3 = __cosf(th3);
      float sp3 = __sinf(ph3), cp3 = __cosf(ph3);
      float st2 = __sinf(th2), ct2 = __cosf(th2);
      float sp2 = __sinf(ph2), cp2 = __cosf(ph2);
      sx += r3v * st3 * cp3 - r2v * st2 * cp2; px[g][k] = sx;
      sy += r3v * st3 * sp3 - r2v * st2 * sp2; py[g][k] = sy;
      sz += r3v * ct3 - r2v * ct2;             pz[g][k] = sz;
    }
    // lane scan of window totals -> exclusive lane offset folded into px
    float ix = sx, iy = sy, iz = sz;
    #pragma unroll
    for (int off = 1; off < 64; off <<= 1) {
      float ax = __shfl_up(ix, off, 64);
      float ay = __shfl_up(iy, off, 64);
      float az = __shfl_up(iz, off, 64);
      if (lane >= off) { ix += ax; iy += ay; iz += az; }
    }
    const float exx = ix - sx, exy = iy - sy, exz = iz - sz;
    #pragma unroll
    for (int k = 0; k < 4; ++k) { px[g][k] += exx; py[g][k] += exy; pz[g][k] += exz; }
    if (lane == 63) {               // window total at its j-position
      wtot[0][wave][gg] = ix; wtot[1][wave][gg] = iy; wtot[2][wave][gg] = iz;
    }
  }
  __syncthreads();

  // ---- Phase 2: j-order offsets from the LDS table ----
  float basex = 0.f, basey = 0.f, basez = 0.f;
  #pragma unroll
  for (int w = 0; w < NW; ++w) {
    if (w < wave) {
      #pragma unroll
      for (int h = 0; h < 4; ++h) {
        basex += wtot[0][w][h]; basey += wtot[1][w][h]; basez += wtot[2][w][h];
      }
    }
  }
  float phx[4], phy[4], phz[4];
  phx[0] = 0.f; phy[0] = 0.f; phz[0] = 0.f;
  #pragma unroll
  for (int h = 1; h < 4; ++h) {
    phx[h] = phx[h-1] + wtot[0][wave][h-1];
    phy[h] = phy[h-1] + wtot[1][wave][h-1];
    phz[h] = phz[h-1] + wtot[2][wave][h-1];
  }

  const float ox = o3[b * 3 + 0] - o2[b * 3 + 0];
  const float oy = o3[b * 3 + 1] - o2[b * 3 + 1];
  const float oz = o3[b * 3 + 2] - o2[b * 3 + 2];
  const float Bx = ox + basex, By = oy + basey, Bz = oz + basez;

  // ---- Phase 3: abs over in-register prefixes ----
  float acc = 0.f;
  #pragma unroll
  for (int g = 0; g < 4; ++g) {
    const int gg = (g + rot) & 3;
    const float sx = (gg == 0) ? phx[0] : (gg == 1) ? phx[1] : (gg == 2) ? phx[2] : phx[3];
    const float sy = (gg == 0) ? phy[0] : (gg == 1) ? phy[1] : (gg == 2) ? phy[2] : phy[3];
    const float sz = (gg == 0) ? phz[0] : (gg == 1) ? phz[1] : (gg == 2) ? phz[2] : phz[3];
    const float gx = Bx + sx, gy = By + sy, gz = Bz + sz;
    #pragma unroll
    for (int k = 0; k < 4; ++k) {
      acc += fabsf(gx + px[g][k]) + fabsf(gy + py[g][k]) + fabsf(gz + pz[g][k]);
    }
  }
  if (t == 0) acc += fabsf(ox) + fabsf(oy) + fabsf(oz);  // j=0 cumsum term

  // ---- block reduction + one atomic per row ----
  #pragma unroll
  for (int off = 32; off > 0; off >>= 1) acc += __shfl_down(acc, off, 64);
  if (lane == 0) redbuf[wave] = acc;
  __syncthreads();
  if (t == 0) {
    float s = 0.f;
    #pragma unroll
    for (int w = 0; w < NW; ++w) s += redbuf[w];
    atomicAdd(out, s * (1.0f / (float)(NPTS + 1)));
  }
}

extern "C" void kernel_launch(void* const* d_in, const int* in_sizes, int n_in,
                              void* d_out, int out_size, void* d_ws, size_t ws_size,
                              hipStream_t stream) {
  const float* o3 = (const float*)d_in[0];  // origin_3D      (B,3,1)
  const float* s3 = (const float*)d_in[1];  // spherical_3D   (B,3,N)
  const float* o2 = (const float*)d_in[2];  // origin_2D      (B,3,1)
  const float* s2 = (const float*)d_in[3];  // spherical_2D   (B,3,N)
  const float* df = (const float*)d_in[4];  // deformation    (B,2,N)
  float* out = (float*)d_out;

  // out accumulates via atomicAdd; harness doesn't re-zero between replays.
  hipMemsetAsync(out, 0, sizeof(float) * out_size, stream);
  row_loss_kernel<<<NBATCH, THREADS, 0, stream>>>(o3, s3, o2, s2, df, out);
}